// Round 11
// baseline (581.777 us; speedup 1.0000x reference)
//
#include <hip/hip_runtime.h>
#include <hip/hip_bf16.h>

// DGL child-sum TreeLSTM, MFMA path, round 27.
// r26 (counted-vmcnt + sched_barrier + 2 blocks/CU) regressed 566->581:
// known failure mode (T3 graft on 2-phase structure; m141 order-pinning).
// Reverted. r27 changes gemm2's wave->work mapping instead: waves split M
// (32 rows/wave), so A is wave-private -> loaded straight to REGISTERS
// (ping-pong aA/aB, static idx), no LDS round-trip, no wave-uniform DMA
// constraint. B (shared) stays DMA+LDS (pre-swizzled wuc). Barrier drains
// 3 DMAs (was 5). LDS 44->25KB. acc 96 + a-regs 16 + misc ~150 <= 170 at
// (256,3). gemm1 and tail = r25 proven forms (tail x4 unroll dropped).
// Facts: inputs fp32 (probed), x/par int32, out fp32.

#define B_G     32
#define NPG     4095
#define NTOT    (B_G * NPG)
#define NCLS    104
#define VOCAB   20000
#define PAD_TOK 19999
#define KCAP    24
#define LB(d)   (32 * ((1 << (d)) - 1))   // level base in level-major order

// convert_kernel block partition
#define EMB_BLKS  2500
#define WUC_BLKS  1536
#define UFC_BLKS  256
#define PREP_BLKS 512
#define CONV_BLKS (EMB_BLKS + WUC_BLKS + UFC_BLKS + PREP_BLKS)

typedef unsigned short u16;
typedef unsigned int   u32;
typedef __attribute__((ext_vector_type(8))) short bfrag8;  // 8 bf16
typedef __attribute__((ext_vector_type(4))) float ffrag4;  // 4 f32

__device__ __forceinline__ float bf2f(u16 v) {
    union { u32 u; float f; } x; x.u = ((u32)v) << 16; return x.f;
}
__device__ __forceinline__ u16 f2bf(float f) {
    union { __hip_bfloat16 h; u16 u; } c; c.h = __float2bfloat16(f); return c.u;
}
__device__ __forceinline__ float loadv(const void* b, int i, int isf32) {
    return isf32 ? ((const float*)b)[i] : bf2f(((const u16*)b)[i]);
}
__device__ __forceinline__ float sigf(float x) { return 1.f / (1.f + __expf(-x)); }

// async global->LDS 16B copy (wave-uniform LDS base + lane*16; per-lane gsrc)
__device__ __forceinline__ void gll16(const u16* g, u16* l) {
    __builtin_amdgcn_global_load_lds(
        (const __attribute__((address_space(1))) u32*)g,
        (__attribute__((address_space(3))) u32*)l, 16, 0, 0);
}

// --------------------------- dtype probe (wave-parallel) --------------------
__global__ __launch_bounds__(384) void probe_kernel(
    const void* emb, const void* Wiou, const void* Uiou,
    const void* Ufw, const void* lw,
    const int* x32, const int* par32, int* flags)
{
    if (blockIdx.x != 0) return;
    const int w = threadIdx.x >> 6, lane = threadIdx.x & 63;
    const void* ptrs[5] = { emb, Wiou, Uiou, Ufw, lw };
    if (w < 5) {
        const u16* p = (const u16*)ptrs[w];
        int big = 0;
        #pragma unroll
        for (int k = 0; k < 2; ++k) {
            u32 e = (((u32)p[lane * 2 + k]) << 16 >> 23) & 0xFF;
            if (e >= 129) ++big;
        }
        unsigned long long m1 = __ballot(big >= 1);
        unsigned long long m2 = __ballot(big >= 2);
        int tot = __popcll(m1) + __popcll(m2);
        if (lane == 0) flags[w] = (tot >= 4) ? 1 : 0;   // 1 => fp32
    } else if (w == 5) {
        int bad = (lane < 8) ? (x32[2 * lane + 1] != 0) : 0;
        unsigned long long mx = __ballot(bad != 0);
        if (lane == 0) {
            flags[5] = (mx == 0) ? 1 : 0;                          // x int64
            flags[6] = (par32[3] == 0 && par32[5] == 0) ? 1 : 0;   // par int64
        }
    }
}

// ---- fused prep: embb conversion + WUc + Ufc + token/bucket prep -----------
// wuc/ufc stored PRE-SWIZZLED: dest 16B-group gq of row `out` takes source
// group gq ^ ((out>>1)&3) (XOR involution). embb stored PLAIN.
__global__ __launch_bounds__(256) void convert_kernel(
    const void* __restrict__ emb, u16* __restrict__ embb,
    const void* __restrict__ Wiou, const void* __restrict__ Uiou,
    u16* __restrict__ wuc,
    const void* __restrict__ Ufw, u16* __restrict__ ufc,
    const int* __restrict__ x, const int* __restrict__ par,
    int* __restrict__ tokLvl, int* __restrict__ cnt, int* __restrict__ bucket,
    const int* __restrict__ flags)
{
    const int b = blockIdx.x;
    if (b < EMB_BLKS) {
        // emb -> bf16 table, PAD row zeroed
        int i8 = (b * 256 + (int)threadIdx.x) * 8;
        if (i8 >= VOCAB * 256) return;
        u16 v[8];
        if ((i8 >> 8) == PAD_TOK) {
            #pragma unroll
            for (int s = 0; s < 8; ++s) v[s] = 0;
        } else if (flags[0]) {
            const float* e = (const float*)emb + i8;
            float4 a = *(const float4*)e;
            float4 c = *(const float4*)(e + 4);
            v[0]=f2bf(a.x); v[1]=f2bf(a.y); v[2]=f2bf(a.z); v[3]=f2bf(a.w);
            v[4]=f2bf(c.x); v[5]=f2bf(c.y); v[6]=f2bf(c.z); v[7]=f2bf(c.w);
        } else {
            *(uint4*)v = *(const uint4*)((const u16*)emb + i8);
        }
        *(uint4*)(embb + i8) = *(uint4*)v;
    } else if (b < EMB_BLKS + WUC_BLKS) {
        // combined [Wiou|Uiou] -> bf16, K-chunked wuc[c][768][32], swizzled
        int idx = (b - EMB_BLKS) * 256 + (int)threadIdx.x;
        if (idx >= 16 * 768 * 32) return;
        int c   = idx / 24576;
        int rem = idx - c * 24576;
        int out = rem >> 5;
        int kk  = rem & 31;
        int kks = (((kk >> 3) ^ ((out >> 1) & 3)) << 3) | (kk & 7);  // swizzle
        int k   = c * 32 + kks;
        float v = (k < 256) ? loadv(Wiou, out * 256 + k, flags[1])
                            : loadv(Uiou, out * 256 + (k - 256), flags[2]);
        wuc[idx] = f2bf(v);
    } else if (b < EMB_BLKS + WUC_BLKS + UFC_BLKS) {
        // Ufw -> bf16, chunked ufc[c][256][32], swizzled
        int idx = (b - EMB_BLKS - WUC_BLKS) * 256 + (int)threadIdx.x;
        if (idx >= 8 * 256 * 32) return;
        int c   = idx >> 13;
        int rem = idx & 8191;
        int out = rem >> 5;
        int kk  = rem & 31;
        int kks = (((kk >> 3) ^ ((out >> 1) & 3)) << 3) | (kk & 7);  // swizzle
        ufc[idx] = f2bf(loadv(Ufw, out * 256 + c * 32 + kks, flags[3]));
    } else {
        // prep: tokens + per-parent child lists
        int gid = (b - EMB_BLKS - WUC_BLKS - UFC_BLKS) * 256 + (int)threadIdx.x;
        if (gid >= NTOT) return;
        int g     = (int)((u32)gid / NPG);
        int local = gid - g * NPG;
        int v  = local + 1;
        int d  = 31 - __clz(v);
        int j  = local - ((1 << d) - 1);
        int tok = flags[5] ? x[2 * gid] : x[gid];
        if (tok < 0 || tok >= VOCAB) tok = PAD_TOK;
        tokLvl[LB(d) + (g << d) + j] = tok;
        if (local > 0) {
            int p  = flags[6] ? par[2 * gid] : par[gid];
            p = max(0, min(p, NTOT - 1));
            int pg = (int)((u32)p / NPG);
            int pl = p - pg * NPG;
            int pd = d - 1;
            int ps = LB(pd) + (pg << pd) + (pl - ((1 << pd) - 1));
            ps = max(0, min(ps, 65503));
            int slot = atomicAdd(&cnt[ps], 1);
            if (slot < KCAP) bucket[(size_t)ps * KCAP + slot] = (g << d) + j;
        }
    }
}

// GEMM1: fc = sigmoid(h_ch @ Ufw^T + b) * c_ch, IN-PLACE over cbuf. M=64.
// r25 form: A and B via global_load_lds into linear LDS; A source-swizzled,
// B table pre-swizzled; squad reads. Double-buffered, one barrier/chunk.
__global__ __launch_bounds__(256, 3) void gemm1_kernel(
    const u16* __restrict__ hch, u16* cbuf,
    const u16* __restrict__ ufc, const void* __restrict__ ufb,
    const int* __restrict__ flags)
{
    __shared__ union {
        struct { u16 As[2][64][32]; u16 Bs[2][256][32]; } k;
        u16 tile[64][264];   // epilogue reuse
    } sm;
    auto& tile = sm.tile;
    const int t = threadIdx.x;
    const int w = t >> 6, lane = t & 63, quad = lane >> 4, l15 = lane & 15;
    const int squad = quad ^ ((l15 >> 1) & 3);   // LDS read swizzle
    const int m0 = blockIdx.x * 64;
    const int f_uf = flags[3];

    const int drow = lane >> 2, dseg = lane & 3;  // A DMA lane mapping
    const int arow = t >> 2, aseg = t & 3;        // B DMA mapping

    ffrag4 acc[4][4];
    #pragma unroll
    for (int i = 0; i < 4; ++i)
        #pragma unroll
        for (int j = 0; j < 4; ++j) acc[i][j] = (ffrag4)0.f;

    // stage chunk cn into buffer buf (all-DMA, 5 DMAs/thread)
    auto stage = [&](int cn, int buf) {
        int row = (w << 4) + drow;
        int ss  = dseg ^ ((row >> 1) & 3);
        gll16(hch + (size_t)(m0 + row) * 256 + cn * 32 + ss * 8,
              &sm.k.As[buf][w << 4][0]);
        #pragma unroll
        for (int r16 = 0; r16 < 4; ++r16)
            gll16(ufc + ((size_t)cn * 256 + r16 * 64 + arow) * 32 + aseg * 8,
                  &sm.k.Bs[buf][r16 * 64 + arow][aseg * 8]);
    };

    stage(0, 0);
    __syncthreads();

    for (int c = 0; c < 8; ++c) {
        const int cur = c & 1, nxt = cur ^ 1;
        if (c + 1 < 8) stage(c + 1, nxt);
        bfrag8 a[4], b[4];
        #pragma unroll
        for (int mt = 0; mt < 4; ++mt) a[mt] = *(bfrag8*)&sm.k.As[cur][mt * 16 + l15][squad * 8];
        #pragma unroll
        for (int nt = 0; nt < 4; ++nt) b[nt] = *(bfrag8*)&sm.k.Bs[cur][w * 64 + nt * 16 + l15][squad * 8];
        #pragma unroll
        for (int mt = 0; mt < 4; ++mt)
            #pragma unroll
            for (int nt = 0; nt < 4; ++nt)
                acc[mt][nt] = __builtin_amdgcn_mfma_f32_16x16x32_bf16(a[mt], b[nt], acc[mt][nt], 0, 0, 0);
        __syncthreads();   // drains vmcnt (DMA) + lgkm; nxt complete
    }

    // ---- epilogue: coalesced c-tile load -> LDS RMW -> coalesced store ----
    const int srow = t >> 2, sseg = t & 3;                 // 4 thr/row, 128B each
    const size_t sgb = (size_t)(m0 + srow) * 256 + sseg * 64;
    #pragma unroll
    for (int k = 0; k < 8; ++k)
        *(uint4*)&tile[srow][sseg * 64 + k * 8] = *(const uint4*)(cbuf + sgb + k * 8);
    __syncthreads();

    #pragma unroll
    for (int nt = 0; nt < 4; ++nt) {
        int hu = w * 64 + nt * 16 + l15;
        float fb = loadv(ufb, hu, f_uf);
        #pragma unroll
        for (int mt = 0; mt < 4; ++mt) {
            #pragma unroll
            for (int r = 0; r < 4; ++r) {
                int row = mt * 16 + quad * 4 + r;
                float f = sigf(acc[mt][nt][r] + fb);
                tile[row][hu] = f2bf(f * bf2f(tile[row][hu]));
            }
        }
    }
    __syncthreads();
    #pragma unroll
    for (int k = 0; k < 8; ++k)
        *(uint4*)(cbuf + sgb + k * 8) = *(const uint4*)&tile[srow][sseg * 64 + k * 8];
}

// agg: htild[p] = sum h_child, cagg[p] = sum fc_child. Coalesced.
__global__ __launch_bounds__(256) void agg_kernel(
    int NN, const u32* __restrict__ hch32, const u32* __restrict__ fcch32,
    const int* __restrict__ cnt_d, const int* __restrict__ bucket_d,
    u32* __restrict__ htild32, u32* __restrict__ cagg32)
{
    int pi  = blockIdx.x * 2 + (threadIdx.x >> 7);
    int col = threadIdx.x & 127;
    if (pi >= NN) return;
    int nc = min(cnt_d[pi], KCAP);
    float h0 = 0.f, h1 = 0.f, c0 = 0.f, c1 = 0.f;
    for (int ci = 0; ci < nc; ++ci) {
        int ch = bucket_d[(size_t)pi * KCAP + ci];
        u32 hv = hch32[(size_t)ch * 128 + col];
        u32 fv = fcch32[(size_t)ch * 128 + col];
        h0 += bf2f((u16)(hv & 0xffff)); h1 += bf2f((u16)(hv >> 16));
        c0 += bf2f((u16)(fv & 0xffff)); c1 += bf2f((u16)(fv >> 16));
    }
    htild32[(size_t)pi * 128 + col] = (u32)f2bf(h0) | ((u32)f2bf(h1) << 16);
    cagg32[(size_t)pi * 128 + col]  = (u32)f2bf(c0) | ((u32)f2bf(c1) << 16);
}

// GEMM2: IOU = [embb[x] | Htild] @ [Wiou|Uiou]^T + gates. M=128, N=192/block.
// r27: waves split M (32 rows/wave); A wave-private -> REGISTERS (ping-pong
// aA/aB); B shared -> DMA+LDS (pre-swizzled wuc, squad read). One barrier
// per chunk draining 3 B-DMAs only.
__global__ __launch_bounds__(256, 3) void gemm2_kernel(
    int nchunk, int NN,
    const int* __restrict__ tokLvl_d, const u16* __restrict__ embb,
    const u16* __restrict__ wuc, const void* __restrict__ biou,
    const u16* __restrict__ htild, const u16* __restrict__ cagg,
    u16* __restrict__ hdst, u16* __restrict__ cdst,
    const int* __restrict__ flags)
{
    __shared__ union {
        u16 Bs[2][192][32];
        u16 tile[128][72];   // epilogue reuse
    } sm;
    __shared__ int toks[128];
    auto& tile = sm.tile;
    const int t = threadIdx.x;
    const int w = t >> 6, lane = t & 63, quad = lane >> 4, l15 = lane & 15;
    const int squad = quad ^ ((l15 >> 1) & 3);   // B LDS read swizzle
    const int m0 = blockIdx.x * 128;
    const int q  = blockIdx.y;
    const int f_b = flags[1];

    if (t < 128) toks[t] = tokLvl_d[m0 + t];
    __syncthreads();

    ffrag4 acc[2][12];   // [mt][g*4+j]; wave rows w*32 + mt*16 + quad*4 + r
    #pragma unroll
    for (int i = 0; i < 2; ++i)
        #pragma unroll
        for (int j = 0; j < 12; ++j) acc[i][j] = (ffrag4)0.f;

    const int brow = t >> 2, bseg = t & 3;        // B DMA mapping
    const int r0 = (w << 5) + l15, r1 = r0 + 16;  // this lane's A rows
    const int tok0 = toks[r0], tok1 = toks[r1];

    auto stageB = [&](int cn, int buf) {
        #pragma unroll
        for (int g = 0; g < 3; ++g)
            gll16(wuc + ((size_t)cn * 768 + g * 256 + q * 64 + brow) * 32 + bseg * 8,
                  &sm.Bs[buf][g * 64 + brow][bseg * 8]);
    };
    auto loadA = [&](int cn, bfrag8* a) {
        if (cn < 8) {
            a[0] = *(const bfrag8*)(embb + (size_t)tok0 * 256 + cn * 32 + quad * 8);
            a[1] = *(const bfrag8*)(embb + (size_t)tok1 * 256 + cn * 32 + quad * 8);
        } else {
            a[0] = *(const bfrag8*)(htild + (size_t)(m0 + r0) * 256 + (cn - 8) * 32 + quad * 8);
            a[1] = *(const bfrag8*)(htild + (size_t)(m0 + r1) * 256 + (cn - 8) * 32 + quad * 8);
        }
    };
    auto mfmaStep = [&](const bfrag8* a, int buf) {
        #pragma unroll
        for (int nt = 0; nt < 12; ++nt) {
            const int g = nt >> 2, j = nt & 3;
            bfrag8 b = *(const bfrag8*)&sm.Bs[buf][g * 64 + j * 16 + l15][squad * 8];
            acc[0][nt] = __builtin_amdgcn_mfma_f32_16x16x32_bf16(a[0], b, acc[0][nt], 0, 0, 0);
            acc[1][nt] = __builtin_amdgcn_mfma_f32_16x16x32_bf16(a[1], b, acc[1][nt], 0, 0, 0);
        }
    };

    bfrag8 aA[2], aB[2];
    loadA(0, aA);
    stageB(0, 0);
    __syncthreads();

    for (int c = 0; c < nchunk; c += 2) {
        // even chunk c: compute from aA / Bs[0]
        stageB(c + 1, 1);
        loadA(c + 1, aB);
        mfmaStep(aA, 0);
        __syncthreads();
        // odd chunk c+1: compute from aB / Bs[1]
        if (c + 2 < nchunk) { stageB(c + 2, 0); loadA(c + 2, aA); }
        mfmaStep(aB, 1);
        __syncthreads();
    }

    // ---- epilogue: LDS-staged, coalesced --------------------------------
    float bias[3][4];
    #pragma unroll
    for (int g = 0; g < 3; ++g)
        #pragma unroll
        for (int j = 0; j < 4; ++j)
            bias[g][j] = loadv(biou, g * 256 + q * 64 + j * 16 + l15, f_b);

    const int srow = t >> 1, sseg = t & 1;   // 2 thr/row, 64B each
    const size_t sgbase = (size_t)(m0 + srow) * 256 + q * 64 + sseg * 32;
    const bool svalid = (m0 + srow) < NN;

    if (cagg) {
        if (svalid) {
            #pragma unroll
            for (int k = 0; k < 4; ++k)
                *(uint4*)&tile[srow][sseg * 32 + k * 8] =
                    *(const uint4*)(cagg + sgbase + k * 8);
        }
    }
    __syncthreads();

    u16 cnv[2][4][4];
    #pragma unroll
    for (int mt = 0; mt < 2; ++mt) {
        #pragma unroll
        for (int j = 0; j < 4; ++j) {
            #pragma unroll
            for (int r = 0; r < 4; ++r) {
                int row  = (w << 5) + mt * 16 + quad * 4 + r;
                int colL = j * 16 + l15;
                float cg = cagg ? bf2f(tile[row][colL]) : 0.f;
                float iv = acc[mt][j][r]     + bias[0][j];
                float ov = acc[mt][4 + j][r] + bias[1][j];
                float uv = acc[mt][8 + j][r] + bias[2][j];
                float cn = sigf(iv) * tanhf(uv) + cg;
                float hn = sigf(ov) * tanhf(cn);
                cnv[mt][j][r] = f2bf(cn);
                tile[row][colL] = f2bf(hn);   // own slot
            }
        }
    }
    __syncthreads();
    if (svalid) {
        #pragma unroll
        for (int k = 0; k < 4; ++k)
            *(uint4*)(hdst + sgbase + k * 8) = *(const uint4*)&tile[srow][sseg * 32 + k * 8];
    }
    __syncthreads();
    #pragma unroll
    for (int mt = 0; mt < 2; ++mt)
        #pragma unroll
        for (int j = 0; j < 4; ++j)
            #pragma unroll
            for (int r = 0; r < 4; ++r)
                tile[(w << 5) + mt * 16 + quad * 4 + r][j * 16 + l15] = cnv[mt][j][r];
    __syncthreads();
    if (svalid) {
        #pragma unroll
        for (int k = 0; k < 4; ++k)
            *(uint4*)(cdst + sgbase + k * 8) = *(const uint4*)&tile[srow][sseg * 32 + k * 8];
    }
}

// tail: levels d=5..0 + final linear; one 1024-thread block/graph (16 waves);
// ALL state in LDS; per-wave N-slice = 16 outputs. r25 version (~108us).
__global__ __launch_bounds__(1024, 1) void tail_kernel(
    const int* __restrict__ tokLvl, const u16* __restrict__ embb,
    const u16* __restrict__ wuc, const void* __restrict__ biou,
    const u16* __restrict__ ufc, const void* __restrict__ ufb,
    const u16* __restrict__ hB, const u16* __restrict__ cB,
    const int* __restrict__ cnt, const int* __restrict__ bucket,
    const void* __restrict__ lw, const void* __restrict__ lb,
    float* __restrict__ out, const int* __restrict__ flags)
{
    __shared__ u16 hs[64][264];    // child h; parent h overwrites rows < np
    __shared__ u16 cs[64][264];    // child c -> fc (stage1) -> parent c
    __shared__ u16 hts[32][264];   // htild
    __shared__ u16 cts[32][264];   // cagg
    __shared__ float lred[8][NCLS];
    __shared__ int cntS[64];       // per-level parents, base 64-(2<<d)
    __shared__ int toksS[64];
    __shared__ int bucketS[64][KCAP];
    const int t = threadIdx.x;     // 0..1023
    const int g = blockIdx.x;
    const int w = t >> 6;          // wave 0..15
    const int lane = t & 63, quad = lane >> 4, l15 = lane & 15;
    const int squad = quad ^ ((l15 >> 1) & 3);   // weight read swizzle
    const int f_uf = flags[3], f_b = flags[1], f_lw = flags[4];
    const int hu = w * 16 + l15;   // this wave's output slice (16 wide)

    // hoisted biases (level-invariant)
    const float fbv = loadv(ufb, hu, f_uf);
    const float biv = loadv(biou, hu,       f_b);
    const float bov = loadv(biou, 256 + hu, f_b);
    const float buv = loadv(biou, 512 + hu, f_b);

    // preload child h,c of d=5 (level 6: 64 rows/graph)
    #pragma unroll 1
    for (int i = t; i < 64 * 32; i += 1024) {
        int j = i >> 5, seg = i & 31;
        size_t off = (((size_t)((g << 6) + j)) << 8) + seg * 8;
        *(uint4*)&hs[j][seg * 8] = *(const uint4*)(hB + off);
        *(uint4*)&cs[j][seg * 8] = *(const uint4*)(cB + off);
    }
    // preload cnt/bucket/tokens for levels d=5..0 (63 parents)
    #pragma unroll 1
    for (int d5 = 5; d5 >= 0; --d5) {
        const int np5  = 1 << d5;
        const int sb5  = 64 - (2 << d5);
        const int lvb5 = LB(d5) + (g << d5);
        #pragma unroll 1
        for (int i = t; i < np5 * (KCAP + 1); i += 1024) {
            int pi = i / (KCAP + 1), f = i - pi * (KCAP + 1);
            if (f == 0) {
                cntS[sb5 + pi]  = cnt[lvb5 + pi];
                toksS[sb5 + pi] = tokLvl[lvb5 + pi];
            } else {
                bucketS[sb5 + pi][f - 1] = bucket[(size_t)(lvb5 + pi) * KCAP + f - 1];
            }
        }
    }
    __syncthreads();

    #pragma unroll 1
    for (int d = 5; d >= 0; --d) {
        const int ncr = 1 << (d + 1);
        const int np  = 1 << d;
        const int sb  = 64 - (2 << d);

        // ---- stage1: cs[j] <- sig(hs[j]@Ufw^T + b) * cs[j]; wave w owns
        //      outputs [w*16, w*16+16). M=64 (4 m-tiles). swizzled ufc read.
        {
            ffrag4 facc[4];
            #pragma unroll
            for (int i = 0; i < 4; ++i) facc[i] = (ffrag4)0.f;
            #pragma unroll 4
            for (int c = 0; c < 8; ++c) {
                bfrag8 a[4];
                #pragma unroll
                for (int mt = 0; mt < 4; ++mt)
                    a[mt] = *(const bfrag8*)&hs[mt * 16 + l15][c * 32 + quad * 8];
                bfrag8 b = *(const bfrag8*)(ufc + ((size_t)c * 256 + w * 16 + l15) * 32 + squad * 8);
                #pragma unroll
                for (int mt = 0; mt < 4; ++mt)
                    facc[mt] = __builtin_amdgcn_mfma_f32_16x16x32_bf16(a[mt], b, facc[mt], 0, 0, 0);
            }
            #pragma unroll
            for (int mt = 0; mt < 4; ++mt) {
                #pragma unroll
                for (int r = 0; r < 4; ++r) {
                    int j = mt * 16 + quad * 4 + r;
                    if (j < ncr) {
                        float f = sigf(facc[mt][r] + fbv);
                        cs[j][hu] = f2bf(f * bf2f(cs[j][hu]));
                    }
                }
            }
        }
        // NO barrier: stage2 reads only this wave's own column slice.

        // ---- stage2: gather htild (hs) + cagg (cs) per parent, wave-own
        //      16-col slice (8 u32 cols), all-LDS ---------------------------
        {
            const int pr = lane >> 3;                   // parent offset 0..7
            const int colb = (w * 8 + (lane & 7)) * 2;  // u16 col base
            #pragma unroll 1
            for (int pi = pr; pi < np; pi += 8) {
                int nc = min(cntS[sb + pi], KCAP);
                float h0 = 0.f, h1 = 0.f, c0 = 0.f, c1 = 0.f;
                #pragma unroll 1
                for (int ci = 0; ci < nc; ++ci) {
                    int j = bucketS[sb + pi][ci] & (ncr - 1);
                    u32 hv = *(const u32*)&hs[j][colb];
                    u32 cv = *(const u32*)&cs[j][colb];
                    h0 += bf2f((u16)(hv & 0xffff)); h1 += bf2f((u16)(hv >> 16));
                    c0 += bf2f((u16)(cv & 0xffff)); c1 += bf2f((u16)(cv >> 16));
                }
                *(u32*)&hts[pi][colb] = (u32)f2bf(h0) | ((u32)f2bf(h1) << 16);
                *(u32*)&cts[pi][colb] = (u32)f2bf(c0) | ((u32)f2bf(c1) << 16);
            }
        }
        __syncthreads();   // B2: hts/cts ready (stage3 reads ALL cols of hts)

        // ---- stage3: [embb|hts] @ WUc + gates; wave w owns hu-tile w of 256
        //      for ALL 3 gates. M=32 (2 m-tiles). swizzled wuc read.
        {
            int tok0 = toksS[sb + min(l15, np - 1)];
            int tok1 = toksS[sb + min(16 + l15, np - 1)];
            const u16* wb = wuc + ((size_t)w * 16 + l15) * 32 + squad * 8;
            ffrag4 acc[2][3];
            #pragma unroll
            for (int i = 0; i < 2; ++i)
                #pragma unroll
                for (int j = 0; j < 3; ++j) acc[i][j] = (ffrag4)0.f;
            // embb phase (c = 0..7)
            #pragma unroll 4
            for (int c = 0; c < 8; ++c) {
                bfrag8 a0 = *(const bfrag8*)(embb + (size_t)tok0 * 256 + c * 32 + quad * 8);
                bfrag8 a1 = *(const bfrag8*)(embb + (size_t)tok1 * 256 + c * 32 + quad * 8);
                #pragma unroll
                for (int g3 = 0; g3 < 3; ++g3) {
                    bfrag8 b = *(const bfrag8*)(wb + ((size_t)c * 768 + g3 * 256) * 32);
                    acc[0][g3] = __builtin_amdgcn_mfma_f32_16x16x32_bf16(a0, b, acc[0][g3], 0, 0, 0);
                    acc[1][g3] = __builtin_amdgcn_mfma_f32_16x16x32_bf16(a1, b, acc[1][g3], 0, 0, 0);
                }
            }
            // htild phase (c = 8..15)
            #pragma unroll 4
            for (int c8 = 0; c8 < 8; ++c8) {
                bfrag8 a0 = *(const bfrag8*)&hts[l15][c8 * 32 + quad * 8];
                bfrag8 a1 = *(const bfrag8*)&hts[16 + l15][c8 * 32 + quad * 8];
                #pragma unroll
                for (int g3 = 0; g3 < 3; ++g3) {
                    bfrag8 b = *(const bfrag8*)(wb + ((size_t)(c8 + 8) * 768 + g3 * 256) * 32);
                    acc[0][g3] = __builtin_amdgcn_mfma_f32_16x16x32_bf16(a0, b, acc[0][g3], 0, 0, 0);
                    acc[1][g3] = __builtin_amdgcn_mfma_f32_16x16x32_bf16(a1, b, acc[1][g3], 0, 0, 0);
                }
            }
            #pragma unroll
            for (int mt = 0; mt < 2; ++mt) {
                #pragma unroll
                for (int r = 0; r < 4; ++r) {
                    int p = mt * 16 + quad * 4 + r;
                    if (p < np) {
                        float iv = acc[mt][0][r] + biv;
                        float ov = acc[mt][1][r] + bov;
                        float uv = acc[mt][2][r] + buv;
                        float cn = sigf(iv) * tanhf(uv) + bf2f(cts[p][hu]);
                        float hn = sigf(ov) * tanhf(cn);
                        hs[p][hu] = f2bf(hn);
                        cs[p][hu] = f2bf(cn);
                    }
                }
            }
        }
        __syncthreads();   // B3: end of level
    }

    // ---- final linear: out[g,:] = h_root @ lw^T + lb, K-split 8x ----------
    {
        const int o  = t & 127;        // output class
        const int ks = t >> 7;         // K-slice 0..7 (32 k each)
        if (o < NCLS) {
            float acc = 0.f;
            #pragma unroll 8
            for (int k = ks * 32; k < ks * 32 + 32; ++k)
                acc += loadv(lw, o * 256 + k, f_lw) * bf2f(hs[0][k]);
            lred[ks][o] = acc;
        }
        __syncthreads();
        if (t < NCLS) {
            float s = 0.f;
            #pragma unroll
            for (int i = 0; i < 8; ++i) s += lred[i][t];
            out[(size_t)g * NCLS + t] = s + loadv(lb, t, f_lw);
        }
    }
}

__global__ void fill_kernel(float* out, int n, float v) {
    int i = blockIdx.x * 256 + threadIdx.x;
    if (i < n) out[i] = v;
}

// ============================ launcher =====================================
extern "C" void kernel_launch(void* const* d_in, const int* in_sizes, int n_in,
                              void* d_out, int out_size, void* d_ws, size_t ws_size,
                              hipStream_t stream)
{
    float* out = (float*)d_out;

    static const int exp_sizes[10] = {131040, 131040, 5120000, 196608, 196608,
                                      768, 65536, 256, 26624, 104};
    bool shapes_ok = (n_in == 10) && (out_size == B_G * NCLS);
    for (int i = 0; i < 10 && shapes_ok; ++i)
        if (in_sizes[i] != exp_sizes[i]) shapes_ok = false;
    if (!shapes_ok) {
        fill_kernel<<<(out_size + 255) / 256, 256, 0, stream>>>(out, out_size, 2.0f);
        return;
    }

    const int* x     = (const int*)d_in[0];
    const int* par   = (const int*)d_in[1];
    const void* emb  = d_in[2];
    const void* Wiou = d_in[3];
    const void* Uiou = d_in[4];
    const void* biou = d_in[5];
    const void* Ufw  = d_in[6];
    const void* Ufb  = d_in[7];
    const void* lw   = d_in[8];
    const void* lb   = d_in[9];

    // -------- workspace layout (byte offsets); total 152,453,184 B --------
    char* W = (char*)d_ws;
    u16* hA     = (u16*)(W + 0);              // bf16 [65536][256] odd levels
    u16* hB     = (u16*)(W + 33554432);       // bf16 [32768][256] even levels
    u16* cA     = (u16*)(W + 50331648);       // bf16 [65536][256] (fc in-place)
    u16* cB     = (u16*)(W + 83886080);       // bf16 [32768][256]
    u16* htild  = (u16*)(W + 100663296);      // bf16 [32768][256]
    u16* cagg   = (u16*)(W + 117440512);      // bf16 [32768][256]
    u16* WUc    = (u16*)(W + 134217728);      // bf16 [16][768][32] (swizzled)
    u16* Ufc    = (u16*)(W + 135004160);      // bf16 [8][256][32] (swizzled)
    int* tokLvl = (int*)(W + 135135232);      // int  [131072]
    int* cnt    = (int*)(W + 135659520);      // int  [65536]
    int* bucket = (int*)(W + 135921664);      // int  [65536*KCAP]
    u16* embb   = (u16*)(W + 142213120);      // bf16 [20000][256]
    int* flags  = (int*)(W + 152453120);      // int  [16]
    const size_t NEED = 152453184;            // <= 152,961,088 known-fit (r7)
    if (ws_size < NEED) {
        fill_kernel<<<(out_size + 255) / 256, 256, 0, stream>>>(out, out_size, 1.0f);
        return;
    }

    hipMemsetAsync(cnt, 0, 65536 * sizeof(int), stream);
    probe_kernel<<<1, 384, 0, stream>>>(emb, Wiou, Uiou, Ufw, lw, x, par, flags);
    convert_kernel<<<CONV_BLKS, 256, 0, stream>>>(
        emb, embb, Wiou, Uiou, WUc, Ufw, Ufc,
        x, par, tokLvl, cnt, bucket, flags);

    // leaves d=11 (odd parity -> hA/cA), K=256
    gemm2_kernel<<<dim3(512, 4), 256, 0, stream>>>(
        8, 65536, tokLvl + LB(11), embb, WUc, biou,
        nullptr, nullptr, hA, cA, flags);

    for (int d = 10; d >= 6; --d) {
        const int cl = d + 1;
        const int NC = B_G << cl;
        const int NN = B_G << d;
        const u16* hch = (cl & 1) ? hA : hB;
        u16*       cch = (cl & 1) ? cA : cB;   // becomes fc in-place
        u16* hdst = (d & 1) ? hA : hB;
        u16* cdst = (d & 1) ? cA : cB;
        gemm1_kernel<<<NC / 64, 256, 0, stream>>>(hch, cch, Ufc, Ufb, flags);
        agg_kernel<<<(NN + 1) / 2, 256, 0, stream>>>(
            NN, (const u32*)hch, (const u32*)cch,
            cnt + LB(d), bucket + (size_t)LB(d) * KCAP,
            (u32*)htild, (u32*)cagg);
        gemm2_kernel<<<dim3((NN + 127) / 128, 4), 256, 0, stream>>>(
            16, NN, tokLvl + LB(d), embb, WUc, biou,
            htild, cagg, hdst, cdst, flags);
    }

    // levels d=5..0 + final linear: one 1024-thread block/graph, LDS-resident
    tail_kernel<<<B_G, 1024, 0, stream>>>(
        tokLvl, embb, WUc, biou, Ufc, Ufb,
        hB, cB, cnt, bucket, lw, lb, out, flags);
}

// Round 12
// 563.083 us; speedup vs baseline: 1.0332x; 1.0332x over previous
//
#include <hip/hip_runtime.h>
#include <hip/hip_bf16.h>

// DGL child-sum TreeLSTM, MFMA path, round 28.
// r27 (M-split gemm2, A in registers) regressed 566->582: per-lane A loads
// serialize against MFMA (nothing to hide under; DMA version overlapped),
// VGPR 68->80. Reverted. Ledger: structural wins = r18 epilogue staging,
// r24 weight swizzle, r25 all-DMA staging; schedule/mapping experiments
// (r22 BK64, r23 dbuf, r26 counted-vmcnt, r27 M-split) all <= neutral.
// r28 = r25 exactly + hoisted token pointers in gemm2's stage (2 LDS
// lookups total, was 16; removes serial LDS->addr dep per stage issue).
// Facts: inputs fp32 (probed), x/par int32, out fp32.

#define B_G     32
#define NPG     4095
#define NTOT    (B_G * NPG)
#define NCLS    104
#define VOCAB   20000
#define PAD_TOK 19999
#define KCAP    24
#define LB(d)   (32 * ((1 << (d)) - 1))   // level base in level-major order

// convert_kernel block partition
#define EMB_BLKS  2500
#define WUC_BLKS  1536
#define UFC_BLKS  256
#define PREP_BLKS 512
#define CONV_BLKS (EMB_BLKS + WUC_BLKS + UFC_BLKS + PREP_BLKS)

typedef unsigned short u16;
typedef unsigned int   u32;
typedef __attribute__((ext_vector_type(8))) short bfrag8;  // 8 bf16
typedef __attribute__((ext_vector_type(4))) float ffrag4;  // 4 f32

__device__ __forceinline__ float bf2f(u16 v) {
    union { u32 u; float f; } x; x.u = ((u32)v) << 16; return x.f;
}
__device__ __forceinline__ u16 f2bf(float f) {
    union { __hip_bfloat16 h; u16 u; } c; c.h = __float2bfloat16(f); return c.u;
}
__device__ __forceinline__ float loadv(const void* b, int i, int isf32) {
    return isf32 ? ((const float*)b)[i] : bf2f(((const u16*)b)[i]);
}
__device__ __forceinline__ float sigf(float x) { return 1.f / (1.f + __expf(-x)); }

// async global->LDS 16B copy (wave-uniform LDS base + lane*16; per-lane gsrc)
__device__ __forceinline__ void gll16(const u16* g, u16* l) {
    __builtin_amdgcn_global_load_lds(
        (const __attribute__((address_space(1))) u32*)g,
        (__attribute__((address_space(3))) u32*)l, 16, 0, 0);
}

// --------------------------- dtype probe (wave-parallel) --------------------
__global__ __launch_bounds__(384) void probe_kernel(
    const void* emb, const void* Wiou, const void* Uiou,
    const void* Ufw, const void* lw,
    const int* x32, const int* par32, int* flags)
{
    if (blockIdx.x != 0) return;
    const int w = threadIdx.x >> 6, lane = threadIdx.x & 63;
    const void* ptrs[5] = { emb, Wiou, Uiou, Ufw, lw };
    if (w < 5) {
        const u16* p = (const u16*)ptrs[w];
        int big = 0;
        #pragma unroll
        for (int k = 0; k < 2; ++k) {
            u32 e = (((u32)p[lane * 2 + k]) << 16 >> 23) & 0xFF;
            if (e >= 129) ++big;
        }
        unsigned long long m1 = __ballot(big >= 1);
        unsigned long long m2 = __ballot(big >= 2);
        int tot = __popcll(m1) + __popcll(m2);
        if (lane == 0) flags[w] = (tot >= 4) ? 1 : 0;   // 1 => fp32
    } else if (w == 5) {
        int bad = (lane < 8) ? (x32[2 * lane + 1] != 0) : 0;
        unsigned long long mx = __ballot(bad != 0);
        if (lane == 0) {
            flags[5] = (mx == 0) ? 1 : 0;                          // x int64
            flags[6] = (par32[3] == 0 && par32[5] == 0) ? 1 : 0;   // par int64
        }
    }
}

// ---- fused prep: embb conversion + WUc + Ufc + token/bucket prep -----------
// wuc/ufc stored PRE-SWIZZLED: dest 16B-group gq of row `out` takes source
// group gq ^ ((out>>1)&3) (XOR involution). embb stored PLAIN (A-side
// swizzle happens in the DMA source address).
__global__ __launch_bounds__(256) void convert_kernel(
    const void* __restrict__ emb, u16* __restrict__ embb,
    const void* __restrict__ Wiou, const void* __restrict__ Uiou,
    u16* __restrict__ wuc,
    const void* __restrict__ Ufw, u16* __restrict__ ufc,
    const int* __restrict__ x, const int* __restrict__ par,
    int* __restrict__ tokLvl, int* __restrict__ cnt, int* __restrict__ bucket,
    const int* __restrict__ flags)
{
    const int b = blockIdx.x;
    if (b < EMB_BLKS) {
        // emb -> bf16 table, PAD row zeroed
        int i8 = (b * 256 + (int)threadIdx.x) * 8;
        if (i8 >= VOCAB * 256) return;
        u16 v[8];
        if ((i8 >> 8) == PAD_TOK) {
            #pragma unroll
            for (int s = 0; s < 8; ++s) v[s] = 0;
        } else if (flags[0]) {
            const float* e = (const float*)emb + i8;
            float4 a = *(const float4*)e;
            float4 c = *(const float4*)(e + 4);
            v[0]=f2bf(a.x); v[1]=f2bf(a.y); v[2]=f2bf(a.z); v[3]=f2bf(a.w);
            v[4]=f2bf(c.x); v[5]=f2bf(c.y); v[6]=f2bf(c.z); v[7]=f2bf(c.w);
        } else {
            *(uint4*)v = *(const uint4*)((const u16*)emb + i8);
        }
        *(uint4*)(embb + i8) = *(uint4*)v;
    } else if (b < EMB_BLKS + WUC_BLKS) {
        // combined [Wiou|Uiou] -> bf16, K-chunked wuc[c][768][32], swizzled
        int idx = (b - EMB_BLKS) * 256 + (int)threadIdx.x;
        if (idx >= 16 * 768 * 32) return;
        int c   = idx / 24576;
        int rem = idx - c * 24576;
        int out = rem >> 5;
        int kk  = rem & 31;
        int kks = (((kk >> 3) ^ ((out >> 1) & 3)) << 3) | (kk & 7);  // swizzle
        int k   = c * 32 + kks;
        float v = (k < 256) ? loadv(Wiou, out * 256 + k, flags[1])
                            : loadv(Uiou, out * 256 + (k - 256), flags[2]);
        wuc[idx] = f2bf(v);
    } else if (b < EMB_BLKS + WUC_BLKS + UFC_BLKS) {
        // Ufw -> bf16, chunked ufc[c][256][32], swizzled
        int idx = (b - EMB_BLKS - WUC_BLKS) * 256 + (int)threadIdx.x;
        if (idx >= 8 * 256 * 32) return;
        int c   = idx >> 13;
        int rem = idx & 8191;
        int out = rem >> 5;
        int kk  = rem & 31;
        int kks = (((kk >> 3) ^ ((out >> 1) & 3)) << 3) | (kk & 7);  // swizzle
        ufc[idx] = f2bf(loadv(Ufw, out * 256 + c * 32 + kks, flags[3]));
    } else {
        // prep: tokens + per-parent child lists
        int gid = (b - EMB_BLKS - WUC_BLKS - UFC_BLKS) * 256 + (int)threadIdx.x;
        if (gid >= NTOT) return;
        int g     = (int)((u32)gid / NPG);
        int local = gid - g * NPG;
        int v  = local + 1;
        int d  = 31 - __clz(v);
        int j  = local - ((1 << d) - 1);
        int tok = flags[5] ? x[2 * gid] : x[gid];
        if (tok < 0 || tok >= VOCAB) tok = PAD_TOK;
        tokLvl[LB(d) + (g << d) + j] = tok;
        if (local > 0) {
            int p  = flags[6] ? par[2 * gid] : par[gid];
            p = max(0, min(p, NTOT - 1));
            int pg = (int)((u32)p / NPG);
            int pl = p - pg * NPG;
            int pd = d - 1;
            int ps = LB(pd) + (pg << pd) + (pl - ((1 << pd) - 1));
            ps = max(0, min(ps, 65503));
            int slot = atomicAdd(&cnt[ps], 1);
            if (slot < KCAP) bucket[(size_t)ps * KCAP + slot] = (g << d) + j;
        }
    }
}

// GEMM1: fc = sigmoid(h_ch @ Ufw^T + b) * c_ch, IN-PLACE over cbuf. M=64.
// r25 form: A and B via global_load_lds into linear LDS; A source-swizzled,
// B table pre-swizzled; squad reads. Double-buffered, one barrier/chunk.
__global__ __launch_bounds__(256, 3) void gemm1_kernel(
    const u16* __restrict__ hch, u16* cbuf,
    const u16* __restrict__ ufc, const void* __restrict__ ufb,
    const int* __restrict__ flags)
{
    __shared__ union {
        struct { u16 As[2][64][32]; u16 Bs[2][256][32]; } k;
        u16 tile[64][264];   // epilogue reuse
    } sm;
    auto& tile = sm.tile;
    const int t = threadIdx.x;
    const int w = t >> 6, lane = t & 63, quad = lane >> 4, l15 = lane & 15;
    const int squad = quad ^ ((l15 >> 1) & 3);   // LDS read swizzle
    const int m0 = blockIdx.x * 64;
    const int f_uf = flags[3];

    const int drow = lane >> 2, dseg = lane & 3;  // A DMA lane mapping
    const int arow = t >> 2, aseg = t & 3;        // B DMA mapping

    ffrag4 acc[4][4];
    #pragma unroll
    for (int i = 0; i < 4; ++i)
        #pragma unroll
        for (int j = 0; j < 4; ++j) acc[i][j] = (ffrag4)0.f;

    // hoisted A-DMA address parts
    const int harow = (w << 4) + drow;
    const int hss   = dseg ^ ((harow >> 1) & 3);
    const u16* habase = hch + (size_t)(m0 + harow) * 256 + hss * 8;

    // stage chunk cn into buffer buf (all-DMA, 5 DMAs/thread)
    auto stage = [&](int cn, int buf) {
        gll16(habase + cn * 32, &sm.k.As[buf][w << 4][0]);
        #pragma unroll
        for (int r16 = 0; r16 < 4; ++r16)
            gll16(ufc + ((size_t)cn * 256 + r16 * 64 + arow) * 32 + aseg * 8,
                  &sm.k.Bs[buf][r16 * 64 + arow][aseg * 8]);
    };

    stage(0, 0);
    __syncthreads();

    for (int c = 0; c < 8; ++c) {
        const int cur = c & 1, nxt = cur ^ 1;
        if (c + 1 < 8) stage(c + 1, nxt);
        bfrag8 a[4], b[4];
        #pragma unroll
        for (int mt = 0; mt < 4; ++mt) a[mt] = *(bfrag8*)&sm.k.As[cur][mt * 16 + l15][squad * 8];
        #pragma unroll
        for (int nt = 0; nt < 4; ++nt) b[nt] = *(bfrag8*)&sm.k.Bs[cur][w * 64 + nt * 16 + l15][squad * 8];
        #pragma unroll
        for (int mt = 0; mt < 4; ++mt)
            #pragma unroll
            for (int nt = 0; nt < 4; ++nt)
                acc[mt][nt] = __builtin_amdgcn_mfma_f32_16x16x32_bf16(a[mt], b[nt], acc[mt][nt], 0, 0, 0);
        __syncthreads();   // drains vmcnt (DMA) + lgkm; nxt complete
    }

    // ---- epilogue: coalesced c-tile load -> LDS RMW -> coalesced store ----
    const int srow = t >> 2, sseg = t & 3;                 // 4 thr/row, 128B each
    const size_t sgb = (size_t)(m0 + srow) * 256 + sseg * 64;
    #pragma unroll
    for (int k = 0; k < 8; ++k)
        *(uint4*)&tile[srow][sseg * 64 + k * 8] = *(const uint4*)(cbuf + sgb + k * 8);
    __syncthreads();

    #pragma unroll
    for (int nt = 0; nt < 4; ++nt) {
        int hu = w * 64 + nt * 16 + l15;
        float fb = loadv(ufb, hu, f_uf);
        #pragma unroll
        for (int mt = 0; mt < 4; ++mt) {
            #pragma unroll
            for (int r = 0; r < 4; ++r) {
                int row = mt * 16 + quad * 4 + r;
                float f = sigf(acc[mt][nt][r] + fb);
                tile[row][hu] = f2bf(f * bf2f(tile[row][hu]));
            }
        }
    }
    __syncthreads();
    #pragma unroll
    for (int k = 0; k < 8; ++k)
        *(uint4*)(cbuf + sgb + k * 8) = *(const uint4*)&tile[srow][sseg * 64 + k * 8];
}

// agg: htild[p] = sum h_child, cagg[p] = sum fc_child. Coalesced.
__global__ __launch_bounds__(256) void agg_kernel(
    int NN, const u32* __restrict__ hch32, const u32* __restrict__ fcch32,
    const int* __restrict__ cnt_d, const int* __restrict__ bucket_d,
    u32* __restrict__ htild32, u32* __restrict__ cagg32)
{
    int pi  = blockIdx.x * 2 + (threadIdx.x >> 7);
    int col = threadIdx.x & 127;
    if (pi >= NN) return;
    int nc = min(cnt_d[pi], KCAP);
    float h0 = 0.f, h1 = 0.f, c0 = 0.f, c1 = 0.f;
    for (int ci = 0; ci < nc; ++ci) {
        int ch = bucket_d[(size_t)pi * KCAP + ci];
        u32 hv = hch32[(size_t)ch * 128 + col];
        u32 fv = fcch32[(size_t)ch * 128 + col];
        h0 += bf2f((u16)(hv & 0xffff)); h1 += bf2f((u16)(hv >> 16));
        c0 += bf2f((u16)(fv & 0xffff)); c1 += bf2f((u16)(fv >> 16));
    }
    htild32[(size_t)pi * 128 + col] = (u32)f2bf(h0) | ((u32)f2bf(h1) << 16);
    cagg32[(size_t)pi * 128 + col]  = (u32)f2bf(c0) | ((u32)f2bf(c1) << 16);
}

// GEMM2: IOU = [embb[x] | Htild] @ [Wiou|Uiou]^T + gates. M=128, N=192/block.
// r25 form: A (embb gather / htild) and B both via global_load_lds; A
// source-swizzled per-lane, squad reads. r28: token pointers hoisted out
// of the stage lambda (2 LDS lookups total, was 16).
__global__ __launch_bounds__(256, 3) void gemm2_kernel(
    int nchunk, int NN,
    const int* __restrict__ tokLvl_d, const u16* __restrict__ embb,
    const u16* __restrict__ wuc, const void* __restrict__ biou,
    const u16* __restrict__ htild, const u16* __restrict__ cagg,
    u16* __restrict__ hdst, u16* __restrict__ cdst,
    const int* __restrict__ flags)
{
    __shared__ union {
        struct { u16 As[2][128][32]; u16 Bs[2][192][32]; } k;
        u16 tile[128][72];   // epilogue reuse
    } sm;
    __shared__ int toks[128];
    auto& tile = sm.tile;
    const int t = threadIdx.x;
    const int w = t >> 6, lane = t & 63, quad = lane >> 4, l15 = lane & 15;
    const int squad = quad ^ ((l15 >> 1) & 3);   // LDS read swizzle
    const int m0 = blockIdx.x * 128;
    const int q  = blockIdx.y;
    const int f_b = flags[1];

    if (t < 128) toks[t] = tokLvl_d[m0 + t];
    __syncthreads();

    ffrag4 acc[8][3];
    #pragma unroll
    for (int i = 0; i < 8; ++i)
        #pragma unroll
        for (int j = 0; j < 3; ++j) acc[i][j] = (ffrag4)0.f;

    const int drow = lane >> 2, dseg = lane & 3;   // A DMA lane mapping
    const int brow = t >> 2, bseg = t & 3;         // B DMA mapping

    // hoisted A-DMA address parts (2 rows per wave)
    const int ar0 = (w << 5) + drow, ar1 = ar0 + 16;
    const int ss0 = dseg ^ ((ar0 >> 1) & 3);
    const int ss1 = dseg ^ ((ar1 >> 1) & 3);
    const u16* eb0 = embb + (size_t)toks[ar0] * 256 + ss0 * 8;
    const u16* eb1 = embb + (size_t)toks[ar1] * 256 + ss1 * 8;
    const u16* hb0 = htild + (size_t)(m0 + ar0) * 256 + ss0 * 8;
    const u16* hb1 = htild + (size_t)(m0 + ar1) * 256 + ss1 * 8;

    // stage chunk cn into buffer buf (all-DMA, 5 DMAs/thread)
    auto stage = [&](int cn, int buf) {
        const u16* s0 = (cn < 8) ? eb0 + cn * 32 : hb0 + (cn - 8) * 32;
        const u16* s1 = (cn < 8) ? eb1 + cn * 32 : hb1 + (cn - 8) * 32;
        gll16(s0, &sm.k.As[buf][w << 5][0]);
        gll16(s1, &sm.k.As[buf][(w << 5) + 16][0]);
        #pragma unroll
        for (int g = 0; g < 3; ++g)
            gll16(wuc + ((size_t)cn * 768 + g * 256 + q * 64 + brow) * 32 + bseg * 8,
                  &sm.k.Bs[buf][g * 64 + brow][bseg * 8]);
    };

    stage(0, 0);
    __syncthreads();

    for (int c = 0; c < nchunk; ++c) {
        const int cur = c & 1, nxt = cur ^ 1;
        if (c + 1 < nchunk) stage(c + 1, nxt);
        bfrag8 a[8], b[3];
        #pragma unroll
        for (int mt = 0; mt < 8; ++mt) a[mt] = *(bfrag8*)&sm.k.As[cur][mt * 16 + l15][squad * 8];
        #pragma unroll
        for (int g = 0; g < 3; ++g) b[g] = *(bfrag8*)&sm.k.Bs[cur][g * 64 + w * 16 + l15][squad * 8];
        #pragma unroll
        for (int mt = 0; mt < 8; ++mt)
            #pragma unroll
            for (int g = 0; g < 3; ++g)
                acc[mt][g] = __builtin_amdgcn_mfma_f32_16x16x32_bf16(a[mt], b[g], acc[mt][g], 0, 0, 0);
        __syncthreads();   // drains vmcnt (DMA) + lgkm; nxt complete
    }

    // ---- epilogue: LDS-staged, coalesced --------------------------------
    const int hu  = q * 64 + w * 16 + l15;   // global column
    const int huL = w * 16 + l15;            // column within 64-wide tile
    const float bi = loadv(biou, hu,       f_b);
    const float bo = loadv(biou, 256 + hu, f_b);
    const float bu = loadv(biou, 512 + hu, f_b);

    const int srow = t >> 1, sseg = t & 1;   // 2 thr/row, 64B each
    const size_t sgbase = (size_t)(m0 + srow) * 256 + q * 64 + sseg * 32;
    const bool svalid = (m0 + srow) < NN;

    if (cagg) {
        if (svalid) {
            #pragma unroll
            for (int k = 0; k < 4; ++k)
                *(uint4*)&tile[srow][sseg * 32 + k * 8] =
                    *(const uint4*)(cagg + sgbase + k * 8);
        }
    }
    __syncthreads();

    u16 cnv[8][4];
    #pragma unroll
    for (int mt = 0; mt < 8; ++mt) {
        #pragma unroll
        for (int r = 0; r < 4; ++r) {
            int row = mt * 16 + quad * 4 + r;
            float cg = cagg ? bf2f(tile[row][huL]) : 0.f;
            float iv = acc[mt][0][r] + bi;
            float ov = acc[mt][1][r] + bo;
            float uv = acc[mt][2][r] + bu;
            float cn = sigf(iv) * tanhf(uv) + cg;
            float hn = sigf(ov) * tanhf(cn);
            cnv[mt][r] = f2bf(cn);
            tile[row][huL] = f2bf(hn);       // own slot: same (row,col) as cg read
        }
    }
    __syncthreads();
    if (svalid) {
        #pragma unroll
        for (int k = 0; k < 4; ++k)
            *(uint4*)(hdst + sgbase + k * 8) = *(const uint4*)&tile[srow][sseg * 32 + k * 8];
    }
    __syncthreads();
    #pragma unroll
    for (int mt = 0; mt < 8; ++mt)
        #pragma unroll
        for (int r = 0; r < 4; ++r)
            tile[mt * 16 + quad * 4 + r][huL] = cnv[mt][r];
    __syncthreads();
    if (svalid) {
        #pragma unroll
        for (int k = 0; k < 4; ++k)
            *(uint4*)(cdst + sgbase + k * 8) = *(const uint4*)&tile[srow][sseg * 32 + k * 8];
    }
}

// tail: levels d=5..0 + final linear; one 1024-thread block/graph (16 waves);
// ALL state in LDS; per-wave N-slice = 16 outputs. r25 version (~108us).
__global__ __launch_bounds__(1024, 1) void tail_kernel(
    const int* __restrict__ tokLvl, const u16* __restrict__ embb,
    const u16* __restrict__ wuc, const void* __restrict__ biou,
    const u16* __restrict__ ufc, const void* __restrict__ ufb,
    const u16* __restrict__ hB, const u16* __restrict__ cB,
    const int* __restrict__ cnt, const int* __restrict__ bucket,
    const void* __restrict__ lw, const void* __restrict__ lb,
    float* __restrict__ out, const int* __restrict__ flags)
{
    __shared__ u16 hs[64][264];    // child h; parent h overwrites rows < np
    __shared__ u16 cs[64][264];    // child c -> fc (stage1) -> parent c
    __shared__ u16 hts[32][264];   // htild
    __shared__ u16 cts[32][264];   // cagg
    __shared__ float lred[8][NCLS];
    __shared__ int cntS[64];       // per-level parents, base 64-(2<<d)
    __shared__ int toksS[64];
    __shared__ int bucketS[64][KCAP];
    const int t = threadIdx.x;     // 0..1023
    const int g = blockIdx.x;
    const int w = t >> 6;          // wave 0..15
    const int lane = t & 63, quad = lane >> 4, l15 = lane & 15;
    const int squad = quad ^ ((l15 >> 1) & 3);   // weight read swizzle
    const int f_uf = flags[3], f_b = flags[1], f_lw = flags[4];
    const int hu = w * 16 + l15;   // this wave's output slice (16 wide)

    // hoisted biases (level-invariant)
    const float fbv = loadv(ufb, hu, f_uf);
    const float biv = loadv(biou, hu,       f_b);
    const float bov = loadv(biou, 256 + hu, f_b);
    const float buv = loadv(biou, 512 + hu, f_b);

    // preload child h,c of d=5 (level 6: 64 rows/graph)
    #pragma unroll 1
    for (int i = t; i < 64 * 32; i += 1024) {
        int j = i >> 5, seg = i & 31;
        size_t off = (((size_t)((g << 6) + j)) << 8) + seg * 8;
        *(uint4*)&hs[j][seg * 8] = *(const uint4*)(hB + off);
        *(uint4*)&cs[j][seg * 8] = *(const uint4*)(cB + off);
    }
    // preload cnt/bucket/tokens for levels d=5..0 (63 parents)
    #pragma unroll 1
    for (int d5 = 5; d5 >= 0; --d5) {
        const int np5  = 1 << d5;
        const int sb5  = 64 - (2 << d5);
        const int lvb5 = LB(d5) + (g << d5);
        #pragma unroll 1
        for (int i = t; i < np5 * (KCAP + 1); i += 1024) {
            int pi = i / (KCAP + 1), f = i - pi * (KCAP + 1);
            if (f == 0) {
                cntS[sb5 + pi]  = cnt[lvb5 + pi];
                toksS[sb5 + pi] = tokLvl[lvb5 + pi];
            } else {
                bucketS[sb5 + pi][f - 1] = bucket[(size_t)(lvb5 + pi) * KCAP + f - 1];
            }
        }
    }
    __syncthreads();

    #pragma unroll 1
    for (int d = 5; d >= 0; --d) {
        const int ncr = 1 << (d + 1);
        const int np  = 1 << d;
        const int sb  = 64 - (2 << d);

        // ---- stage1: cs[j] <- sig(hs[j]@Ufw^T + b) * cs[j]; wave w owns
        //      outputs [w*16, w*16+16). M=64 (4 m-tiles). swizzled ufc read.
        {
            ffrag4 facc[4];
            #pragma unroll
            for (int i = 0; i < 4; ++i) facc[i] = (ffrag4)0.f;
            #pragma unroll 4
            for (int c = 0; c < 8; ++c) {
                bfrag8 a[4];
                #pragma unroll
                for (int mt = 0; mt < 4; ++mt)
                    a[mt] = *(const bfrag8*)&hs[mt * 16 + l15][c * 32 + quad * 8];
                bfrag8 b = *(const bfrag8*)(ufc + ((size_t)c * 256 + w * 16 + l15) * 32 + squad * 8);
                #pragma unroll
                for (int mt = 0; mt < 4; ++mt)
                    facc[mt] = __builtin_amdgcn_mfma_f32_16x16x32_bf16(a[mt], b, facc[mt], 0, 0, 0);
            }
            #pragma unroll
            for (int mt = 0; mt < 4; ++mt) {
                #pragma unroll
                for (int r = 0; r < 4; ++r) {
                    int j = mt * 16 + quad * 4 + r;
                    if (j < ncr) {
                        float f = sigf(facc[mt][r] + fbv);
                        cs[j][hu] = f2bf(f * bf2f(cs[j][hu]));
                    }
                }
            }
        }
        // NO barrier: stage2 reads only this wave's own column slice.

        // ---- stage2: gather htild (hs) + cagg (cs) per parent, wave-own
        //      16-col slice (8 u32 cols), all-LDS ---------------------------
        {
            const int pr = lane >> 3;                   // parent offset 0..7
            const int colb = (w * 8 + (lane & 7)) * 2;  // u16 col base
            #pragma unroll 1
            for (int pi = pr; pi < np; pi += 8) {
                int nc = min(cntS[sb + pi], KCAP);
                float h0 = 0.f, h1 = 0.f, c0 = 0.f, c1 = 0.f;
                #pragma unroll 1
                for (int ci = 0; ci < nc; ++ci) {
                    int j = bucketS[sb + pi][ci] & (ncr - 1);
                    u32 hv = *(const u32*)&hs[j][colb];
                    u32 cv = *(const u32*)&cs[j][colb];
                    h0 += bf2f((u16)(hv & 0xffff)); h1 += bf2f((u16)(hv >> 16));
                    c0 += bf2f((u16)(cv & 0xffff)); c1 += bf2f((u16)(cv >> 16));
                }
                *(u32*)&hts[pi][colb] = (u32)f2bf(h0) | ((u32)f2bf(h1) << 16);
                *(u32*)&cts[pi][colb] = (u32)f2bf(c0) | ((u32)f2bf(c1) << 16);
            }
        }
        __syncthreads();   // B2: hts/cts ready (stage3 reads ALL cols of hts)

        // ---- stage3: [embb|hts] @ WUc + gates; wave w owns hu-tile w of 256
        //      for ALL 3 gates. M=32 (2 m-tiles). swizzled wuc read.
        {
            int tok0 = toksS[sb + min(l15, np - 1)];
            int tok1 = toksS[sb + min(16 + l15, np - 1)];
            const u16* wb = wuc + ((size_t)w * 16 + l15) * 32 + squad * 8;
            ffrag4 acc[2][3];
            #pragma unroll
            for (int i = 0; i < 2; ++i)
                #pragma unroll
                for (int j = 0; j < 3; ++j) acc[i][j] = (ffrag4)0.f;
            // embb phase (c = 0..7)
            #pragma unroll 4
            for (int c = 0; c < 8; ++c) {
                bfrag8 a0 = *(const bfrag8*)(embb + (size_t)tok0 * 256 + c * 32 + quad * 8);
                bfrag8 a1 = *(const bfrag8*)(embb + (size_t)tok1 * 256 + c * 32 + quad * 8);
                #pragma unroll
                for (int g3 = 0; g3 < 3; ++g3) {
                    bfrag8 b = *(const bfrag8*)(wb + ((size_t)c * 768 + g3 * 256) * 32);
                    acc[0][g3] = __builtin_amdgcn_mfma_f32_16x16x32_bf16(a0, b, acc[0][g3], 0, 0, 0);
                    acc[1][g3] = __builtin_amdgcn_mfma_f32_16x16x32_bf16(a1, b, acc[1][g3], 0, 0, 0);
                }
            }
            // htild phase (c = 8..15)
            #pragma unroll 4
            for (int c8 = 0; c8 < 8; ++c8) {
                bfrag8 a0 = *(const bfrag8*)&hts[l15][c8 * 32 + quad * 8];
                bfrag8 a1 = *(const bfrag8*)&hts[16 + l15][c8 * 32 + quad * 8];
                #pragma unroll
                for (int g3 = 0; g3 < 3; ++g3) {
                    bfrag8 b = *(const bfrag8*)(wb + ((size_t)(c8 + 8) * 768 + g3 * 256) * 32);
                    acc[0][g3] = __builtin_amdgcn_mfma_f32_16x16x32_bf16(a0, b, acc[0][g3], 0, 0, 0);
                    acc[1][g3] = __builtin_amdgcn_mfma_f32_16x16x32_bf16(a1, b, acc[1][g3], 0, 0, 0);
                }
            }
            #pragma unroll
            for (int mt = 0; mt < 2; ++mt) {
                #pragma unroll
                for (int r = 0; r < 4; ++r) {
                    int p = mt * 16 + quad * 4 + r;
                    if (p < np) {
                        float iv = acc[mt][0][r] + biv;
                        float ov = acc[mt][1][r] + bov;
                        float uv = acc[mt][2][r] + buv;
                        float cn = sigf(iv) * tanhf(uv) + bf2f(cts[p][hu]);
                        float hn = sigf(ov) * tanhf(cn);
                        hs[p][hu] = f2bf(hn);
                        cs[p][hu] = f2bf(cn);
                    }
                }
            }
        }
        __syncthreads();   // B3: end of level
    }

    // ---- final linear: out[g,:] = h_root @ lw^T + lb, K-split 8x ----------
    {
        const int o  = t & 127;        // output class
        const int ks = t >> 7;         // K-slice 0..7 (32 k each)
        if (o < NCLS) {
            float acc = 0.f;
            #pragma unroll 8
            for (int k = ks * 32; k < ks * 32 + 32; ++k)
                acc += loadv(lw, o * 256 + k, f_lw) * bf2f(hs[0][k]);
            lred[ks][o] = acc;
        }
        __syncthreads();
        if (t < NCLS) {
            float s = 0.f;
            #pragma unroll
            for (int i = 0; i < 8; ++i) s += lred[i][t];
            out[(size_t)g * NCLS + t] = s + loadv(lb, t, f_lw);
        }
    }
}

__global__ void fill_kernel(float* out, int n, float v) {
    int i = blockIdx.x * 256 + threadIdx.x;
    if (i < n) out[i] = v;
}

// ============================ launcher =====================================
extern "C" void kernel_launch(void* const* d_in, const int* in_sizes, int n_in,
                              void* d_out, int out_size, void* d_ws, size_t ws_size,
                              hipStream_t stream)
{
    float* out = (float*)d_out;

    static const int exp_sizes[10] = {131040, 131040, 5120000, 196608, 196608,
                                      768, 65536, 256, 26624, 104};
    bool shapes_ok = (n_in == 10) && (out_size == B_G * NCLS);
    for (int i = 0; i < 10 && shapes_ok; ++i)
        if (in_sizes[i] != exp_sizes[i]) shapes_ok = false;
    if (!shapes_ok) {
        fill_kernel<<<(out_size + 255) / 256, 256, 0, stream>>>(out, out_size, 2.0f);
        return;
    }

    const int* x     = (const int*)d_in[0];
    const int* par   = (const int*)d_in[1];
    const void* emb  = d_in[2];
    const void* Wiou = d_in[3];
    const void* Uiou = d_in[4];
    const void* biou = d_in[5];
    const void* Ufw  = d_in[6];
    const void* Ufb  = d_in[7];
    const void* lw   = d_in[8];
    const void* lb   = d_in[9];

    // -------- workspace layout (byte offsets); total 152,453,184 B --------
    char* W = (char*)d_ws;
    u16* hA     = (u16*)(W + 0);              // bf16 [65536][256] odd levels
    u16* hB     = (u16*)(W + 33554432);       // bf16 [32768][256] even levels
    u16* cA     = (u16*)(W + 50331648);       // bf16 [65536][256] (fc in-place)
    u16* cB     = (u16*)(W + 83886080);       // bf16 [32768][256]
    u16* htild  = (u16*)(W + 100663296);      // bf16 [32768][256]
    u16* cagg   = (u16*)(W + 117440512);      // bf16 [32768][256]
    u16* WUc    = (u16*)(W + 134217728);      // bf16 [16][768][32] (swizzled)
    u16* Ufc    = (u16*)(W + 135004160);      // bf16 [8][256][32] (swizzled)
    int* tokLvl = (int*)(W + 135135232);      // int  [131072]
    int* cnt    = (int*)(W + 135659520);      // int  [65536]
    int* bucket = (int*)(W + 135921664);      // int  [65536*KCAP]
    u16* embb   = (u16*)(W + 142213120);      // bf16 [20000][256]
    int* flags  = (int*)(W + 152453120);      // int  [16]
    const size_t NEED = 152453184;            // <= 152,961,088 known-fit (r7)
    if (ws_size < NEED) {
        fill_kernel<<<(out_size + 255) / 256, 256, 0, stream>>>(out, out_size, 1.0f);
        return;
    }

    hipMemsetAsync(cnt, 0, 65536 * sizeof(int), stream);
    probe_kernel<<<1, 384, 0, stream>>>(emb, Wiou, Uiou, Ufw, lw, x, par, flags);
    convert_kernel<<<CONV_BLKS, 256, 0, stream>>>(
        emb, embb, Wiou, Uiou, WUc, Ufw, Ufc,
        x, par, tokLvl, cnt, bucket, flags);

    // leaves d=11 (odd parity -> hA/cA), K=256
    gemm2_kernel<<<dim3(512, 4), 256, 0, stream>>>(
        8, 65536, tokLvl + LB(11), embb, WUc, biou,
        nullptr, nullptr, hA, cA, flags);

    for (int d = 10; d >= 6; --d) {
        const int cl = d + 1;
        const int NC = B_G << cl;
        const int NN = B_G << d;
        const u16* hch = (cl & 1) ? hA : hB;
        u16*       cch = (cl & 1) ? cA : cB;   // becomes fc in-place
        u16* hdst = (d & 1) ? hA : hB;
        u16* cdst = (d & 1) ? cA : cB;
        gemm1_kernel<<<NC / 64, 256, 0, stream>>>(hch, cch, Ufc, Ufb, flags);
        agg_kernel<<<(NN + 1) / 2, 256, 0, stream>>>(
            NN, (const u32*)hch, (const u32*)cch,
            cnt + LB(d), bucket + (size_t)LB(d) * KCAP,
            (u32*)htild, (u32*)cagg);
        gemm2_kernel<<<dim3((NN + 127) / 128, 4), 256, 0, stream>>>(
            16, NN, tokLvl + LB(d), embb, WUc, biou,
            htild, cagg, hdst, cdst, flags);
    }

    // levels d=5..0 + final linear: one 1024-thread block/graph, LDS-resident
    tail_kernel<<<B_G, 1024, 0, stream>>>(
        tokLvl, embb, WUc, biou, Ufc, Ufb,
        hB, cB, cnt, bucket, lw, lb, out, flags);
}